// Round 1
// 163.880 us; speedup vs baseline: 1.0170x; 1.0170x over previous
//
#include <hip/hip_runtime.h>

#define BATCH 16
#define CCH   256
#define WLEN  4096
#define OCH   256
#define KW    3
#define CK    768      // CCH*KW
#define WIN   96       // x-window floats per channel
#define CHUNK 32       // channels per K-chunk
#define NCHUNK 8       // CCH / CHUNK
#define SLD   104      // Sl row stride (shorts): 96 ck + 8 pad, keeps 16B align

typedef short bf16x8 __attribute__((ext_vector_type(8)));
typedef short bf16x4 __attribute__((ext_vector_type(4)));
typedef float f32x4  __attribute__((ext_vector_type(4)));

__device__ inline short f2bf(float f) {
    union { float f; unsigned u; } v; v.f = f;
    unsigned r = v.u + 0x7FFFu + ((v.u >> 16) & 1u);   // RNE
    return (short)(r >> 16);
}

__device__ inline void gl_lds16(const void* g, void* l) {
    __builtin_amdgcn_global_load_lds(
        (const __attribute__((address_space(1))) unsigned int*)g,
        (__attribute__((address_space(3))) unsigned int*)l, 16, 0, 0);
}

// ---------------- kernel 1: weight fp32 [256][768] -> bf16 ----------------
__global__ void wconv_kernel(const float* __restrict__ w, short* __restrict__ wb) {
    int i = blockIdx.x * 256 + threadIdx.x;
    wb[i] = f2bf(w[i]);
}

// ---------------- fused kernel v2: 8 waves, 32-ch chunks, dual double-buffer ----------------
// grid: 16 b x 64 wt = 1024 blocks, 512 thr (8 waves) -> 2 blocks/CU, exactly 2 rounds.
// Wave wv owns oc rows [wv*32, wv*32+32): acc[2][4] = 32 AGPRs (vs 64 before).
// Per chunk iteration (ONE barrier): issue DMA(c+2) -> Win[(c)&1], gather(c+1) from
// Win[(c+1)&1] -> Sl[(c+1)&1], MFMA(c) from Sl[c&1]. DMA drain hidden under gather+MFMA.
__global__ __launch_bounds__(512, 4)
void deform_fused_kernel(const float* __restrict__ x,
                         const short* __restrict__ wb,
                         const float* __restrict__ off,
                         const float* __restrict__ msk,
                         const float* __restrict__ bias,
                         float* __restrict__ out) {
    __shared__ float WinS[2][CHUNK * WIN];   // 2 x 12288 B: chunk windows
    __shared__ short SlS[2][64 * SLD];       // 2 x 13312 B: gathered B-tile [w][96ck]

    const int t      = threadIdx.x;
    const int b      = blockIdx.x >> 6;
    const int wt     = blockIdx.x & 63;
    const int lane   = t & 63;
    const int wv     = t >> 6;
    const int lr     = lane & 15;
    const int lq     = lane >> 4;
    const int wstart = wt * 64 - 16;
    const int wg     = wt * 64 + lane;

    // ---- per-lane sampling params (identical math to validated kernel) ----
    int   li[3];
    float rw0[3], rw1[3];
#pragma unroll
    for (int k = 0; k < 3; ++k) {
        float o  = off[b * (KW * WLEN) + k * WLEN + wg];
        float m  = msk[b * (KW * WLEN) + k * WLEN + wg];
        float p  = (float)(wg - 1 + k) + o;
        float pf = floorf(p);
        float w1 = p - pf;
        int i0 = (int)pf;
        int i1 = i0 + 1;
        bool v0 = (i0 >= 0) & (i0 < WLEN);
        bool v1 = (i1 >= 0) & (i1 < WLEN);
        li[k]  = min(max(i0 - wstart, 0), WIN - 2);   // row[li], row[li+1] both in-window
        rw0[k] = v0 ? m * (1.0f - w1) : 0.0f;
        rw1[k] = v1 ? m * w1 : 0.0f;
    }

    const float* xb = x + (size_t)b * CCH * WLEN;

    // ---- staging source offsets (lane-static): 768 float4 slots per chunk ----
    // slot s -> ch = s/24, o16 = s%24; instr A covers slots [0,512), B covers [512,768)
    const int sA = t;
    const int chA = sA / 24, oA = sA - chA * 24;
    const int jA  = min(max(wstart + oA * 4, 0), WLEN - 4);
    const int offA = chA * WLEN + jA;
    const int sB = 512 + t;
    const int chB = sB / 24, oB = sB - chB * 24;
    const int jB  = min(max(wstart + oB * 4, 0), WLEN - 4);
    const int offB = chB * WLEN + jB;

    f32x4 acc[2][4];
#pragma unroll
    for (int i = 0; i < 2; ++i)
#pragma unroll
        for (int j = 0; j < 4; ++j)
            acc[i][j] = (f32x4){0.f, 0.f, 0.f, 0.f};

    // ---- stage chunk c's windows into WinS[bufsel]: 12 KB via 16B DMA ----
    auto stage = [&](int c, int bufsel) {
        const float* src = xb + (size_t)c * CHUNK * WLEN;
        gl_lds16(src + offA, &WinS[bufsel][wv * 256]);
        if (wv < 4) gl_lds16(src + offB, &WinS[bufsel][2048 + wv * 256]);
    };

    // ---- gather chunk (parity bufsel): wave wv samples its 4 channels ----
    auto gather = [&](int bufsel) {
        short obuf[12];
#pragma unroll
        for (int dc = 0; dc < 4; ++dc) {
            const float* row = &WinS[bufsel][(wv * 4 + dc) * WIN];
#pragma unroll
            for (int k = 0; k < 3; ++k) {
                float v0 = row[li[k]];
                float v1 = row[li[k] + 1];
                obuf[dc * 3 + k] = f2bf(rw0[k] * v0 + rw1[k] * v1);
            }
        }
        short* sp = &SlS[bufsel][lane * SLD + wv * 12];   // cols [wv*12, wv*12+12)
#pragma unroll
        for (int j = 0; j < 3; ++j)
            *reinterpret_cast<bf16x4*>(sp + j * 4) =
                *reinterpret_cast<const bf16x4*>(&obuf[j * 4]);
    };

    // ---- MFMA chunk c: A-frags from global (L2-hot wb), B-frags from SlS ----
    auto mfma_chunk = [&](int c, int bufsel) {
#pragma unroll
        for (int ks = 0; ks < 3; ++ks) {
            bf16x8 af[2], bfv[4];
#pragma unroll
            for (int mt = 0; mt < 2; ++mt)
                af[mt] = *reinterpret_cast<const bf16x8*>(
                    wb + (size_t)(wv * 32 + mt * 16 + lr) * CK + c * 96 + ks * 32 + lq * 8);
#pragma unroll
            for (int nt = 0; nt < 4; ++nt)
                bfv[nt] = *reinterpret_cast<const bf16x8*>(
                    &SlS[bufsel][(nt * 16 + lr) * SLD + ks * 32 + lq * 8]);
#pragma unroll
            for (int mt = 0; mt < 2; ++mt)
#pragma unroll
                for (int nt = 0; nt < 4; ++nt)
                    acc[mt][nt] = __builtin_amdgcn_mfma_f32_16x16x32_bf16(
                        af[mt], bfv[nt], acc[mt][nt], 0, 0, 0);
        }
    };

    // ---- prologue: Win[0]=chunk0 drained; Win[1]=chunk1 drained; Sl[0]=gather(0) ----
    stage(0, 0);
    __syncthreads();               // drains DMA(0)
    stage(1, 1);
    gather(0);                     // reads Win[0], writes Sl[0]
    __syncthreads();               // drains DMA(1), Sl[0] visible

    // ---- main loop: one barrier per chunk, everything overlapped ----
#pragma unroll 2
    for (int c = 0; c < NCHUNK; ++c) {
        if (c < NCHUNK - 2) stage(c + 2, c & 1);      // Win[c&1] free (chunk c gathered last iter)
        if (c < NCHUNK - 1) gather((c + 1) & 1);      // Win[(c+1)&1] -> Sl[(c+1)&1]
        mfma_chunk(c, c & 1);                         // Sl[c&1]
        if (c < NCHUNK - 1) __syncthreads();          // drains DMA(c+2) + Sl writes
    }

    // ---- epilogue: D row = lq*4+reg (oc), col = lr (w) ----
    float* ob = out + ((size_t)b * OCH) * WLEN + wt * 64;
#pragma unroll
    for (int mt = 0; mt < 2; ++mt) {
#pragma unroll
        for (int r = 0; r < 4; ++r) {
            int row = wv * 32 + mt * 16 + lq * 4 + r;
            float bv = bias[row];
            float* orow = ob + (size_t)row * WLEN + lr;
#pragma unroll
            for (int nt = 0; nt < 4; ++nt)
                orow[nt * 16] = acc[mt][nt][r] + bv;
        }
    }
}

extern "C" void kernel_launch(void* const* d_in, const int* in_sizes, int n_in,
                              void* d_out, int out_size, void* d_ws, size_t ws_size,
                              hipStream_t stream) {
    const float* x    = (const float*)d_in[0];
    const float* w    = (const float*)d_in[1];
    const float* off  = (const float*)d_in[2];
    const float* msk  = (const float*)d_in[3];
    const float* bias = (const float*)d_in[4];
    float* out = (float*)d_out;
    short* wb  = (short*)d_ws;   // 384 KB bf16 weights

    wconv_kernel<<<768, 256, 0, stream>>>(w, wb);
    deform_fused_kernel<<<BATCH * 64, 512, 0, stream>>>(x, wb, off, msk, bias, out);
}

// Round 2
// 162.172 us; speedup vs baseline: 1.0277x; 1.0105x over previous
//
#include <hip/hip_runtime.h>

#define BATCH 16
#define CCH   256
#define WLEN  4096
#define OCH   256
#define KW    3
#define CK    768      // CCH*KW
#define WIN   96       // x-window floats per channel
#define CHUNK 32       // channels per K-chunk
#define NCHUNK 8       // CCH / CHUNK
#define SLD   104      // Sl row stride (shorts): 96 ck + 8 pad, keeps 16B align

typedef short bf16x8 __attribute__((ext_vector_type(8)));
typedef short bf16x4 __attribute__((ext_vector_type(4)));
typedef float f32x4  __attribute__((ext_vector_type(4)));

__device__ inline short f2bf(float f) {
    union { float f; unsigned u; } v; v.f = f;
    unsigned r = v.u + 0x7FFFu + ((v.u >> 16) & 1u);   // RNE
    return (short)(r >> 16);
}

__device__ inline void gl_lds16(const void* g, void* l) {
    __builtin_amdgcn_global_load_lds(
        (const __attribute__((address_space(1))) unsigned int*)g,
        (__attribute__((address_space(3))) unsigned int*)l, 16, 0, 0);
}

template<int N> __device__ inline void vmwait() {
    if constexpr (N == 0)      asm volatile("s_waitcnt vmcnt(0)" ::: "memory");
    else if constexpr (N == 1) asm volatile("s_waitcnt vmcnt(1)" ::: "memory");
    else if constexpr (N == 2) asm volatile("s_waitcnt vmcnt(2)" ::: "memory");
    else if constexpr (N == 4) asm volatile("s_waitcnt vmcnt(4)" ::: "memory");
}
__device__ inline void lgkm0() { asm volatile("s_waitcnt lgkmcnt(0)" ::: "memory"); }

// ---------------- kernel 1: weight fp32 [256][768] -> bf16 ----------------
__global__ void wconv_kernel(const float* __restrict__ w, short* __restrict__ wb) {
    int i = blockIdx.x * 256 + threadIdx.x;
    wb[i] = f2bf(w[i]);
}

// ---------------- fused kernel v3: depth-3 DMA pipeline, counted vmcnt ----------------
// grid: 16 b x 64 wt = 1024 blocks, 512 thr (8 waves), 2 blocks/CU.
// Win[3] (12KB each): chunk c+1 staged two iterations before gather(c+1) reads it.
// Per iter: vmcnt(N, counted) -> lgkmcnt(0) -> s_barrier -> stage(c+3) -> gather(c+1)
//           -> mfma(c). DMA stays in flight ACROSS the barrier (no vmcnt(0) drain).
__global__ __launch_bounds__(512, 4)
void deform_fused_kernel(const float* __restrict__ x,
                         const short* __restrict__ wb,
                         const float* __restrict__ off,
                         const float* __restrict__ msk,
                         const float* __restrict__ bias,
                         float* __restrict__ out) {
    __shared__ float WinS[3][CHUNK * WIN];   // 3 x 12288 B: chunk windows
    __shared__ short SlS[2][64 * SLD];       // 2 x 13312 B: gathered B-tile [w][96ck]

    const int t      = threadIdx.x;
    const int b      = blockIdx.x >> 6;
    const int wt     = blockIdx.x & 63;
    const int lane   = t & 63;
    const int wv     = t >> 6;
    const int lr     = lane & 15;
    const int lq     = lane >> 4;
    const int wstart = wt * 64 - 16;
    const int wg     = wt * 64 + lane;

    // ---- per-lane sampling params (identical math to validated kernel) ----
    int   li[3];
    float rw0[3], rw1[3];
#pragma unroll
    for (int k = 0; k < 3; ++k) {
        float o  = off[b * (KW * WLEN) + k * WLEN + wg];
        float m  = msk[b * (KW * WLEN) + k * WLEN + wg];
        float p  = (float)(wg - 1 + k) + o;
        float pf = floorf(p);
        float w1 = p - pf;
        int i0 = (int)pf;
        int i1 = i0 + 1;
        bool v0 = (i0 >= 0) & (i0 < WLEN);
        bool v1 = (i1 >= 0) & (i1 < WLEN);
        li[k]  = min(max(i0 - wstart, 0), WIN - 2);   // row[li], row[li+1] both in-window
        rw0[k] = v0 ? m * (1.0f - w1) : 0.0f;
        rw1[k] = v1 ? m * w1 : 0.0f;
    }

    const float* xb = x + (size_t)b * CCH * WLEN;

    // ---- staging source offsets (lane-static): 768 float4 slots per chunk ----
    const int sA = t;
    const int chA = sA / 24, oA = sA - chA * 24;
    const int jA  = min(max(wstart + oA * 4, 0), WLEN - 4);
    const int offA = chA * WLEN + jA;
    const int sB = 512 + t;
    const int chB = sB / 24, oB = sB - chB * 24;
    const int jB  = min(max(wstart + oB * 4, 0), WLEN - 4);
    const int offB = chB * WLEN + jB;

    f32x4 acc[2][4];
#pragma unroll
    for (int i = 0; i < 2; ++i)
#pragma unroll
        for (int j = 0; j < 4; ++j)
            acc[i][j] = (f32x4){0.f, 0.f, 0.f, 0.f};

    // ---- stage chunk c's windows into WinS[bufsel] (waves 0-3: 2 DMA, 4-7: 1 DMA) ----
    auto stage = [&](int c, int bufsel) {
        const float* src = xb + (size_t)c * CHUNK * WLEN;
        gl_lds16(src + offA, &WinS[bufsel][wv * 256]);
        if (wv < 4) gl_lds16(src + offB, &WinS[bufsel][2048 + wv * 256]);
    };

    // ---- gather: wave wv samples its 4 channels from WinS[wbuf] -> SlS[sbuf] ----
    auto gather = [&](int wbuf, int sbuf) {
        short obuf[12];
#pragma unroll
        for (int dc = 0; dc < 4; ++dc) {
            const float* row = &WinS[wbuf][(wv * 4 + dc) * WIN];
#pragma unroll
            for (int k = 0; k < 3; ++k) {
                float v0 = row[li[k]];
                float v1 = row[li[k] + 1];
                obuf[dc * 3 + k] = f2bf(rw0[k] * v0 + rw1[k] * v1);
            }
        }
        short* sp = &SlS[sbuf][lane * SLD + wv * 12];   // cols [wv*12, wv*12+12)
#pragma unroll
        for (int j = 0; j < 3; ++j)
            *reinterpret_cast<bf16x4*>(sp + j * 4) =
                *reinterpret_cast<const bf16x4*>(&obuf[j * 4]);
    };

    // ---- MFMA chunk c: A-frags from global (L2-hot wb), B-frags from SlS[sbuf] ----
    auto mfma_chunk = [&](int c, int sbuf) {
#pragma unroll
        for (int ks = 0; ks < 3; ++ks) {
            bf16x8 af[2], bfv[4];
#pragma unroll
            for (int mt = 0; mt < 2; ++mt)
                af[mt] = *reinterpret_cast<const bf16x8*>(
                    wb + (size_t)(wv * 32 + mt * 16 + lr) * CK + c * 96 + ks * 32 + lq * 8);
#pragma unroll
            for (int nt = 0; nt < 4; ++nt)
                bfv[nt] = *reinterpret_cast<const bf16x8*>(
                    &SlS[sbuf][(nt * 16 + lr) * SLD + ks * 32 + lq * 8]);
            __builtin_amdgcn_s_setprio(1);
#pragma unroll
            for (int mt = 0; mt < 2; ++mt)
#pragma unroll
                for (int nt = 0; nt < 4; ++nt)
                    acc[mt][nt] = __builtin_amdgcn_mfma_f32_16x16x32_bf16(
                        af[mt], bfv[nt], acc[mt][nt], 0, 0, 0);
            __builtin_amdgcn_s_setprio(0);
        }
    };

    // ---- prologue: stage chunks 0,1,2; wait only chunk 0; gather(0) ----
    stage(0, 0);
    stage(1, 1);
    stage(2, 2);
    if (wv < 4) vmwait<4>(); else vmwait<2>();   // S(0) landed; S(1),S(2) in flight
    __builtin_amdgcn_s_barrier();
    gather(0, 0);

    // ---- main pipeline: one barrier per chunk, DMA never fully drained ----
#define ITER_FULL(c)                                                  \
    if (wv < 4) vmwait<2>(); else vmwait<1>();  /* S(c+1) landed */   \
    lgkm0();                                                          \
    __builtin_amdgcn_s_barrier();                                     \
    stage((c) + 3, (c) % 3);                                          \
    gather(((c) + 1) % 3, ((c) + 1) & 1);                             \
    mfma_chunk((c), (c) & 1);

    ITER_FULL(0)
    ITER_FULL(1)
    ITER_FULL(2)
    ITER_FULL(3)
    ITER_FULL(4)
#undef ITER_FULL

    // c = 5: no more staging (S(7) was last); S(6) must land
    if (wv < 4) vmwait<2>(); else vmwait<1>();
    lgkm0();
    __builtin_amdgcn_s_barrier();
    gather(0, 0);          // chunk 6 -> Win[6%3=0], Sl[0]
    mfma_chunk(5, 1);

    // c = 6: S(7) must land (last outstanding)
    vmwait<0>();
    lgkm0();
    __builtin_amdgcn_s_barrier();
    gather(1, 1);          // chunk 7 -> Win[7%3=1], Sl[1]
    mfma_chunk(6, 0);

    // c = 7
    lgkm0();
    __builtin_amdgcn_s_barrier();
    mfma_chunk(7, 1);

    // ---- epilogue: D row = lq*4+reg (oc), col = lr (w) ----
    float* ob = out + ((size_t)b * OCH) * WLEN + wt * 64;
#pragma unroll
    for (int mt = 0; mt < 2; ++mt) {
#pragma unroll
        for (int r = 0; r < 4; ++r) {
            int row = wv * 32 + mt * 16 + lq * 4 + r;
            float bv = bias[row];
            float* orow = ob + (size_t)row * WLEN + lr;
#pragma unroll
            for (int nt = 0; nt < 4; ++nt)
                orow[nt * 16] = acc[mt][nt][r] + bv;
        }
    }
}

extern "C" void kernel_launch(void* const* d_in, const int* in_sizes, int n_in,
                              void* d_out, int out_size, void* d_ws, size_t ws_size,
                              hipStream_t stream) {
    const float* x    = (const float*)d_in[0];
    const float* w    = (const float*)d_in[1];
    const float* off  = (const float*)d_in[2];
    const float* msk  = (const float*)d_in[3];
    const float* bias = (const float*)d_in[4];
    float* out = (float*)d_out;
    short* wb  = (short*)d_ws;   // 384 KB bf16 weights

    wconv_kernel<<<768, 256, 0, stream>>>(w, wb);
    deform_fused_kernel<<<BATCH * 64, 512, 0, stream>>>(x, wb, off, msk, bias, out);
}